// Round 6
// baseline (218.137 us; speedup 1.0000x reference)
//
#include <hip/hip_runtime.h>
#include <hip/hip_fp16.h>
#include <math.h>

#define PI_D 3.141592653589793

typedef _Float16 h2 __attribute__((ext_vector_type(2)));
typedef _Float16 h4 __attribute__((ext_vector_type(4)));
typedef _Float16 h8 __attribute__((ext_vector_type(8)));
typedef unsigned short us8 __attribute__((ext_vector_type(8)));
typedef __fp16 f16v2 __attribute__((ext_vector_type(2)));
typedef __fp16 f16v8 __attribute__((ext_vector_type(8)));
typedef float f32x4 __attribute__((ext_vector_type(4)));

#define STR1 264     // gl1h/gr1h row stride in halves (528 B; 33 h8)
#define STR2H 72     // gl2h/gr2h fp16 row stride in halves (144 B)

#define SV(v, a, b) __builtin_shufflevector(v, v, a, b)

static __device__ __forceinline__ h2 pack_h2(float a, float b) {
    return __builtin_bit_cast(h2, __builtin_amdgcn_cvt_pkrtz(a, b));
}

static __device__ __forceinline__ float fdot2(h2 a, h2 b, float c) {
    return __builtin_amdgcn_fdot2(__builtin_bit_cast(f16v2, a),
                                  __builtin_bit_cast(f16v2, b), c, false);
}

static __device__ __forceinline__ h8 habs8(h8 x) {
    us8 u = __builtin_bit_cast(us8, x);
    us8 m = {0x7fff, 0x7fff, 0x7fff, 0x7fff, 0x7fff, 0x7fff, 0x7fff, 0x7fff};
    return __builtin_bit_cast(h8, (us8)(u & m));
}

static __device__ __forceinline__ f32x4 mfma16(h8 a, h8 b, f32x4 c) {
    return __builtin_amdgcn_mfma_f32_16x16x32_f16(
        __builtin_bit_cast(f16v8, a), __builtin_bit_cast(f16v8, b), c, 0, 0, 0);
}

// 512 threads (8 waves) per sample, grid = B. Total waves 8192 -> 32/CU
// (was 4096 -> 16/CU). Rationale: measured VALUBusy scales ~linearly with
// resident waves (8w/CU: 20%, 16w/CU: 47%); per-thread work halves, total
// inst ~constant, so kernel time ~ const / busy%.
__global__ __launch_bounds__(512, 8) void actor_fused_kernel(
    const float* __restrict__ state24,
    const float* __restrict__ Wl1, const float* __restrict__ Wr1,
    const float* __restrict__ att1, const float* __restrict__ b1,
    const float* __restrict__ Wl2, const float* __restrict__ Wr2,
    const float* __restrict__ att2, const float* __restrict__ b2,
    const float* __restrict__ fc1_w, const float* __restrict__ fc1_b,
    const float* __restrict__ fc2_w, const float* __restrict__ fc2_b,
    const float* __restrict__ fc3_w, const float* __restrict__ fc3_b,
    float* __restrict__ out, int B)
{
    const int smp = blockIdx.x;
    const int tid = threadIdx.x;
    const int wid = tid >> 6;        // 0..7
    const int lane = tid & 63;

    __shared__ float sinL[20], cosL[20], laserL[20], robotL[4];
    __shared__ __align__(16) h2 attLh[128];
    __shared__ __align__(16) h2 att2Lh[32];
    __shared__ __align__(16) _Float16 gr1h[22 * STR1];
    __shared__ __align__(16) union {
        struct { _Float16 gl1h[22 * STR1];
                 float ePf[128 * 24];
                 float uv[168]; } p1;
        struct { _Float16 gl2h[21 * STR2H];
                 _Float16 gr2h[21 * STR2H];
                 _Float16 gl2hT[64 * 32];
                 float e2[32 * 24];
                 float u2v2[42];
                 float red[8][256];
                 _Float16 nfvh[64]; _Float16 hah[256]; _Float16 hbh[256]; } p2;
    } U;

    // ---- setup ----
    if (tid < 20) {
        double step = (PI_D + 0.03) / 20.0;
        float bound = (float)(-PI_D / 2.0 - 0.03 + (double)tid * step);
        float ang = bound + (float)(PI_D / 20.0);
        sinL[tid] = sinf(ang);
        cosL[tid] = cosf(ang);
        laserL[tid] = state24[smp * 24 + tid] * 0.1f;
    }
    if (tid >= 32 && tid < 36) {
        int q = tid - 32;
        robotL[q] = state24[smp * 24 + 20 + q];
    }
    if (tid < 128) {
        float2 ap = ((const float2*)att1)[tid];
        attLh[tid] = pack_h2(0.4f * ap.x, 0.4f * ap.y);
    }
    if (tid >= 128 && tid < 160) {
        float2 ap = ((const float2*)att2)[tid - 128];
        att2Lh[tid - 128] = pack_h2(0.4f * ap.x, 0.4f * ap.y);
    }
    __syncthreads();

    // ---- transform1: 512 threads = 128 h2-cols x 4 node-quarters ----
    {
        const int d2 = tid & 127;
        const int qtr = tid >> 7;        // 0..3: nodes qtr*6 .. qtr*6+5 (qtr3: 3)
        float2 wl[7], wr[7];
        #pragma unroll
        for (int k = 0; k < 7; k++) {
            wl[k] = ((const float2*)Wl1)[k * 128 + d2];
            wr[k] = ((const float2*)Wr1)[k * 128 + d2];
        }
        if (qtr == 0) {
            h2 zz2 = {};
            ((h2*)(U.p1.gl1h + 21 * STR1))[d2] = zz2;
            ((h2*)(gr1h + 21 * STR1))[d2] = zz2;
        }
        const int base = qtr * 6;
        #pragma unroll
        for (int nn = 0; nn < 6; ++nn) {
            int node = base + nn;
            if (node < 21) {
                float a0, a1, b0, b1v;
                if (node < 20) {
                    float l = laserL[node], sv = sinL[node], c = cosL[node];
                    a0 = l * wl[0].x + sv * wl[1].x + c * wl[2].x;
                    a1 = l * wl[0].y + sv * wl[1].y + c * wl[2].y;
                    b0 = l * wr[0].x + sv * wr[1].x + c * wr[2].x;
                    b1v = l * wr[0].y + sv * wr[1].y + c * wr[2].y;
                } else {
                    float r0 = robotL[0], r1 = robotL[1], r2 = robotL[2], r3 = robotL[3];
                    a0 = r0 * wl[3].x + r1 * wl[4].x + r2 * wl[5].x + r3 * wl[6].x;
                    a1 = r0 * wl[3].y + r1 * wl[4].y + r2 * wl[5].y + r3 * wl[6].y;
                    b0 = r0 * wr[3].x + r1 * wr[4].x + r2 * wr[5].x + r3 * wr[6].x;
                    b1v = r0 * wr[3].y + r1 * wr[4].y + r2 * wr[5].y + r3 * wr[6].y;
                }
                ((h2*)(U.p1.gl1h + node * STR1))[d2] = pack_h2(a0, a1);
                ((h2*)(gr1h + node * STR1))[d2] = pack_h2(b0, b1v);
            }
        }
    }
    __syncthreads();

    // ---- logits1: wave pair (2h, 2h+1) covers head h; p = pair-index 0..127
    //      = (j, 4-wide i-strip); gl[j] cached in regs; u/v on sub0 lanes ----
    {
        const int h = wid >> 1;
        const int p = (wid & 1) * 64 + lane;       // 0..127
        h2 ar[32];
        #pragma unroll
        for (int q = 0; q < 32; ++q) ar[q] = attLh[h * 32 + q];

        const bool act = p < 126;
        const int jn  = act ? p % 21 : 0;
        const int seg = act ? p / 21 : 0;          // 0..5

        const h8* gA8 = (const h8*)(U.p1.gl1h + jn * STR1 + h * 64);
        h8 gj[8];
        #pragma unroll
        for (int ch = 0; ch < 8; ++ch) gj[ch] = gA8[ch];

        if (act && seg == 0) {                     // u_j (p = 0..20)
            float l0 = 0.f, l1 = 0.f;
            #pragma unroll
            for (int ch = 0; ch < 8; ++ch) {
                l0 = fdot2(SV(gj[ch], 0, 1), ar[ch * 4 + 0], l0);
                l1 = fdot2(SV(gj[ch], 2, 3), ar[ch * 4 + 1], l1);
                l0 = fdot2(SV(gj[ch], 4, 5), ar[ch * 4 + 2], l0);
                l1 = fdot2(SV(gj[ch], 6, 7), ar[ch * 4 + 3], l1);
            }
            U.p1.uv[h * 21 + jn] = l0 + l1;
        }

        #pragma unroll
        for (int t = 0; t < 4; ++t) {
            const int i = seg * 4 + t;             // 0..23, guard <21
            if (i < 21) {
                const h8* gB8 = (const h8*)(gr1h + i * STR1 + h * 64);
                float m0 = 0.f, m1 = 0.f;
                #pragma unroll
                for (int ch = 0; ch < 8; ++ch) {
                    h8 x = gj[ch] + gB8[ch];
                    h8 ax = habs8(x);
                    m0 = fdot2(SV(ax, 0, 1), ar[ch * 4 + 0], m0);
                    m1 = fdot2(SV(ax, 2, 3), ar[ch * 4 + 1], m1);
                    m0 = fdot2(SV(ax, 4, 5), ar[ch * 4 + 2], m0);
                    m1 = fdot2(SV(ax, 6, 7), ar[ch * 4 + 3], m1);
                }
                if (act) U.p1.ePf[(h * 32 + i) * 24 + jn] = m0 + m1;
            }
        }

        if (p >= 21 && p < 42) {                   // v_i (sub0 lanes 21..41)
            const int idx = p - 21;
            const h8* row8 = (const h8*)(gr1h + idx * STR1 + h * 64);
            float l0 = 0.f, l1 = 0.f;
            #pragma unroll
            for (int ch = 0; ch < 8; ++ch) {
                h8 g = row8[ch];
                l0 = fdot2(SV(g, 0, 1), ar[ch * 4 + 0], l0);
                l1 = fdot2(SV(g, 2, 3), ar[ch * 4 + 1], l1);
                l0 = fdot2(SV(g, 4, 5), ar[ch * 4 + 2], l0);
                l1 = fdot2(SV(g, 6, 7), ar[ch * 4 + 3], l1);
            }
            U.p1.uv[84 + h * 21 + idx] = l0 + l1;
        }
    }
    __syncthreads();

    // ---- softmax1: wave pair per head; sub0 rows 0..10, sub1 rows 11..20 ----
    {
        const int h = wid >> 1;
        const int sub = wid & 1;
        if (lane < 11 - sub) {
            int i = sub * 11 + lane;
            int r = h * 32 + i;
            float* row = U.p1.ePf + r * 24;
            const float* uu = U.p1.uv + h * 21;
            float vi = 1.5f * U.p1.uv[84 + h * 21 + i];
            float ebuf[21];
            float m = -1e30f;
            #pragma unroll
            for (int j = 0; j < 21; j++) {
                float e = row[j] + 1.5f * uu[j] + vi;
                ebuf[j] = e;
                m = fmaxf(m, e);
            }
            float sum = 0.f;
            #pragma unroll
            for (int j = 0; j < 21; j++) { float v = __expf(ebuf[j] - m); ebuf[j] = v; sum += v; }
            float rinv = 1.f / sum;
            h8* hp8 = (h8*)(U.p1.ePf) + r * 6;
            h8 o0, o1, o2;
            #pragma unroll
            for (int q = 0; q < 8; ++q) o0[q] = (_Float16)(ebuf[q] * rinv);
            #pragma unroll
            for (int q = 0; q < 8; ++q) o1[q] = (_Float16)(ebuf[8 + q] * rinv);
            #pragma unroll
            for (int q = 0; q < 5; ++q) o2[q] = (_Float16)(ebuf[16 + q] * rinv);
            o2[5] = (_Float16)0.f; o2[6] = (_Float16)0.f; o2[7] = (_Float16)0.f;
            h8 zz = {};
            hp8[0] = o0; hp8[1] = o1; hp8[2] = o2;
            hp8[3] = zz; hp8[4] = zz; hp8[5] = zz;
        }
        {   // zero fp16 A-frag rows (h, 21..31): 66 h8 over the wave pair
            int z = sub * 64 + lane;
            if (z < 66) {
                int rr = z / 6, slot = z - rr * 6;
                h8 zz = {};
                ((h8*)U.p1.ePf)[(h * 32 + 21 + rr) * 6 + slot] = zz;
            }
        }
    }
    __syncthreads();

    // ---- agg1 via MFMA: wave pair per head; sub = A0/A1 row-half ----
    {
        const int h = wid >> 1;
        const int sub = wid & 1;
        const int mcol = lane & 15;
        const int quad = lane >> 4;
        const h8* Af = (const h8*)U.p1.ePf;
        h8 A = Af[(h * 32 + sub * 16 + mcol) * 6 + quad];   // rows>=21 are zeros
        int rowoff[8];
        #pragma unroll
        for (int jj = 0; jj < 8; ++jj) {
            int rr = quad * 8 + jj;
            rowoff[jj] = (rr > 21 ? 21 : rr) * STR1;
        }
        const int colbase = h * 64 + mcol;
        f32x4 z4 = {0.f, 0.f, 0.f, 0.f};
        #pragma unroll
        for (int t = 0; t < 4; ++t) {
            int col = colbase + t * 16;
            float bb = b1[col];
            h8 bv;
            #pragma unroll
            for (int jj = 0; jj < 8; ++jj) bv[jj] = U.p1.gl1h[rowoff[jj] + col];
            f32x4 d = mfma16(A, bv, z4);
            #pragma unroll
            for (int r = 0; r < 4; ++r) {
                int n = sub * 16 + quad * 4 + r;
                if (n < 21) {
                    float v = d[r] + bb;
                    v = v > 0.f ? v : __expf(v) - 1.f;
                    gr1h[n * STR1 + col] = (_Float16)v;
                }
            }
        }
    }
    __syncthreads();

    // ---- layer-2 transforms via MFMA: 8 waves = 4 ntiles x 2 row-halves;
    //      B-frags converted inline from fp32 (RNE, same layout as before) ----
    {
        const int ntile = wid >> 1;      // 0..3
        const int rhalf = wid & 1;
        const int mrow = lane & 15;
        const int quad = lane >> 4;
        int arow = rhalf ? (16 + mrow > 21 ? 21 : 16 + mrow) : mrow;
        const int ncol = ntile * 16 + mrow;
        const float* pL = Wl2 + ncol;
        const float* pR = Wr2 + ncol;
        f32x4 aL = {0.f, 0.f, 0.f, 0.f}, aR = {0.f, 0.f, 0.f, 0.f};
        #pragma unroll
        for (int kc = 0; kc < 8; ++kc) {
            const int kb = kc * 32 + quad * 8;
            h8 BL, BR;
            #pragma unroll
            for (int j = 0; j < 8; ++j) {
                BL[j] = (_Float16)pL[(kb + j) * 64];
                BR[j] = (_Float16)pR[(kb + j) * 64];
            }
            h8 A = *(const h8*)(gr1h + arow * STR1 + quad * 8 + kc * 32);
            aL = mfma16(A, BL, aL);
            aR = mfma16(A, BR, aR);
        }
        const int col = ncol;
        #pragma unroll
        for (int r = 0; r < 4; ++r) {
            int row = rhalf * 16 + quad * 4 + r;
            if (row < 21) {
                U.p2.gl2h[row * STR2H + col] = (_Float16)aL[r];
                U.p2.gr2h[row * STR2H + col] = (_Float16)aR[r];
            }
        }
        h2 lo = pack_h2(aL[0], aL[1]);
        h2 hi = pack_h2(aL[2], aL[3]);
        h4 pq = __builtin_shufflevector(lo, hi, 0, 1, 2, 3);
        *(h4*)(U.p2.gl2hT + col * 32 + rhalf * 16 + quad * 4) = pq;  // rows>=21 are zeros
    }
    __syncthreads();

    // ---- layer-2 logits: 1 duty per thread (441 pairs + 21 u2 + 21 v2) ----
    {
        h2 ar2[32];
        #pragma unroll
        for (int q = 0; q < 32; ++q) ar2[q] = att2Lh[q];

        const int p = tid;
        if (p < 441) {
            const int i = p / 21;
            const int jn = p - i * 21;
            const h8* gA8 = (const h8*)(U.p2.gl2h + jn * STR2H);
            const h8* gB8 = (const h8*)(U.p2.gr2h + i * STR2H);
            float m0 = 0.f, m1 = 0.f;
            #pragma unroll
            for (int ch = 0; ch < 8; ++ch) {
                h8 x = gA8[ch] + gB8[ch];
                h8 ax = habs8(x);
                m0 = fdot2(SV(ax, 0, 1), ar2[ch * 4 + 0], m0);
                m1 = fdot2(SV(ax, 2, 3), ar2[ch * 4 + 1], m1);
                m0 = fdot2(SV(ax, 4, 5), ar2[ch * 4 + 2], m0);
                m1 = fdot2(SV(ax, 6, 7), ar2[ch * 4 + 3], m1);
            }
            U.p2.e2[i * 24 + jn] = m0 + m1;
        } else if (p < 483) {
            const int isV = p >= 462;
            const int j = p - (isV ? 462 : 441);
            const h8* row8 = (const h8*)((isV ? U.p2.gr2h : U.p2.gl2h) + j * STR2H);
            float l0 = 0.f, l1 = 0.f;
            #pragma unroll
            for (int ch = 0; ch < 8; ++ch) {
                h8 g = row8[ch];
                l0 = fdot2(SV(g, 0, 1), ar2[ch * 4 + 0], l0);
                l1 = fdot2(SV(g, 2, 3), ar2[ch * 4 + 1], l1);
                l0 = fdot2(SV(g, 4, 5), ar2[ch * 4 + 2], l0);
                l1 = fdot2(SV(g, 6, 7), ar2[ch * 4 + 3], l1);
            }
            U.p2.u2v2[isV * 21 + j] = l0 + l1;
        }
    }
    __syncthreads();

    // ---- softmax-2 ----
    if (tid < 21) {
        int i = tid;
        float* row = U.p2.e2 + i * 24;
        const float* uu = U.p2.u2v2;
        float vi = 1.5f * U.p2.u2v2[21 + i];
        float ebuf[21];
        float m = -1e30f;
        #pragma unroll
        for (int j = 0; j < 21; j++) {
            float e = row[j] + 1.5f * uu[j] + vi;
            ebuf[j] = e;
            m = fmaxf(m, e);
        }
        float sum = 0.f;
        #pragma unroll
        for (int j = 0; j < 21; j++) { float v = __expf(ebuf[j] - m); ebuf[j] = v; sum += v; }
        float rinv = 1.f / sum;
        h8* hp8 = (h8*)(U.p2.e2) + i * 6;
        h8 o0, o1, o2;
        #pragma unroll
        for (int q = 0; q < 8; ++q) o0[q] = (_Float16)(ebuf[q] * rinv);
        #pragma unroll
        for (int q = 0; q < 8; ++q) o1[q] = (_Float16)(ebuf[8 + q] * rinv);
        #pragma unroll
        for (int q = 0; q < 5; ++q) o2[q] = (_Float16)(ebuf[16 + q] * rinv);
        o2[5] = (_Float16)0.f; o2[6] = (_Float16)0.f; o2[7] = (_Float16)0.f;
        h8 zz = {};
        hp8[0] = o0; hp8[1] = o1; hp8[2] = o2;
        hp8[3] = zz; hp8[4] = zz; hp8[5] = zz;
    } else if (tid < 87) {
        int z = tid - 21;                 // rows 21..31 x 6 slots
        int rr = z / 6, slot = z - rr * 6;
        h8 zz = {};
        ((h8*)U.p2.e2)[(21 + rr) * 6 + slot] = zz;
    }
    __syncthreads();

    // ---- agg2 + mean-pool via MFMA -> nfvh (waves 0..3) ----
    if (wid < 4) {
        const int mcol = lane & 15;
        const int quad = lane >> 4;
        const int col = wid * 16 + mcol;
        float bb = b2[col];
        f32x4 z4 = {0.f, 0.f, 0.f, 0.f};
        const h8* Af2 = (const h8*)U.p2.e2;
        h8 A0 = Af2[mcol * 6 + quad];
        h8 A1 = Af2[(16 + mcol) * 6 + quad];
        h8 bv = *(const h8*)(U.p2.gl2hT + col * 32 + quad * 8);
        f32x4 d0 = mfma16(A0, bv, z4);
        f32x4 d1 = mfma16(A1, bv, z4);
        float sum = (d0[0] + d0[1]) + (d0[2] + d0[3])
                  + (d1[0] + d1[1]) + (d1[2] + d1[3]);
        sum += __shfl_xor(sum, 16, 64);
        sum += __shfl_xor(sum, 32, 64);
        if (quad == 0) U.p2.nfvh[col] = (_Float16)(sum * (1.f / 21.f) + bb);
    }
    __syncthreads();

    // ---- FC1 (64 -> 256): fp32 weights direct, k split 8 ways ----
    {
        int c = tid & 63, g = tid >> 6;            // g 0..7
        const float4* W1 = (const float4*)fc1_w;   // [64 rows][64 float4]
        float4 acc = {0.f, 0.f, 0.f, 0.f};
        #pragma unroll
        for (int kk = 0; kk < 4; ++kk) {
            int k2 = g * 4 + kk;
            float4 r0 = W1[(2 * k2) * 64 + c];
            float4 r1 = W1[(2 * k2 + 1) * 64 + c];
            h2 x = ((const h2*)U.p2.nfvh)[k2];
            float x0 = (float)x[0], x1 = (float)x[1];
            acc.x = fmaf(r0.x, x0, fmaf(r1.x, x1, acc.x));
            acc.y = fmaf(r0.y, x0, fmaf(r1.y, x1, acc.y));
            acc.z = fmaf(r0.z, x0, fmaf(r1.z, x1, acc.z));
            acc.w = fmaf(r0.w, x0, fmaf(r1.w, x1, acc.w));
        }
        ((float4*)U.p2.red[g])[c] = acc;
    }
    __syncthreads();
    if (tid < 256) {
        float v = fc1_b[tid];
        #pragma unroll
        for (int g = 0; g < 8; ++g) v += U.p2.red[g][tid];
        U.p2.hah[tid] = (_Float16)fmaxf(v, 0.f);
    }
    __syncthreads();

    // ---- FC2 (256 -> 256): fp32 weights direct, k split 8 ways ----
    {
        int c = tid & 63, g = tid >> 6;
        const float4* W2 = (const float4*)fc2_w;   // [256 rows][64 float4]
        const h8* ha = (const h8*)U.p2.hah;
        float4 acc = {0.f, 0.f, 0.f, 0.f};
        #pragma unroll
        for (int q = 0; q < 4; ++q) {
            h8 xa = ha[g * 4 + q];
            #pragma unroll
            for (int pp = 0; pp < 4; ++pp) {
                int k2 = g * 16 + q * 4 + pp;
                float4 r0 = W2[(2 * k2) * 64 + c];
                float4 r1 = W2[(2 * k2 + 1) * 64 + c];
                float x0 = (float)xa[2 * pp], x1 = (float)xa[2 * pp + 1];
                acc.x = fmaf(r0.x, x0, fmaf(r1.x, x1, acc.x));
                acc.y = fmaf(r0.y, x0, fmaf(r1.y, x1, acc.y));
                acc.z = fmaf(r0.z, x0, fmaf(r1.z, x1, acc.z));
                acc.w = fmaf(r0.w, x0, fmaf(r1.w, x1, acc.w));
            }
        }
        ((float4*)U.p2.red[g])[c] = acc;
    }
    __syncthreads();
    if (tid < 256) {
        float v = fc2_b[tid];
        #pragma unroll
        for (int g = 0; g < 8; ++g) v += U.p2.red[g][tid];
        U.p2.hbh[tid] = (_Float16)fmaxf(v, 0.f);
    }
    __syncthreads();

    // ---- FC3 (256 -> 2) + tanh: waves 0,1 own outputs 0,1 ----
    {
        int g = tid >> 6;
        if (g < 2) {
            int o = g;
            int l = tid & 63;
            float sum = 0.f;
            #pragma unroll
            for (int m = 0; m < 4; m++) {
                int k = l + 64 * m;
                sum = fmaf((float)U.p2.hbh[k], fc3_w[k * 2 + o], sum);
            }
            #pragma unroll
            for (int off = 32; off >= 1; off >>= 1) sum += __shfl_down(sum, off, 64);
            if (l == 0) out[smp * 2 + o] = tanhf(sum + fc3_b[o]);
        }
    }
}

extern "C" void kernel_launch(void* const* d_in, const int* in_sizes, int n_in,
                              void* d_out, int out_size, void* d_ws, size_t ws_size,
                              hipStream_t stream) {
    const float* state24 = (const float*)d_in[0];
    const float* Wl1 = (const float*)d_in[1];
    const float* Wr1 = (const float*)d_in[2];
    const float* att1 = (const float*)d_in[3];
    const float* b1 = (const float*)d_in[4];
    const float* Wl2 = (const float*)d_in[5];
    const float* Wr2 = (const float*)d_in[6];
    const float* att2 = (const float*)d_in[7];
    const float* b2 = (const float*)d_in[8];
    const float* fc1_w = (const float*)d_in[9];
    const float* fc1_b = (const float*)d_in[10];
    const float* fc2_w = (const float*)d_in[11];
    const float* fc2_b = (const float*)d_in[12];
    const float* fc3_w = (const float*)d_in[13];
    const float* fc3_b = (const float*)d_in[14];
    float* out = (float*)d_out;

    (void)d_ws; (void)ws_size;          // single-dispatch: no workspace needed

    int B = in_sizes[0] / 24;
    actor_fused_kernel<<<B, 512, 0, stream>>>(
        state24, Wl1, Wr1, att1, b1, Wl2, Wr2, att2, b2,
        fc1_w, fc1_b, fc2_w, fc2_b, fc3_w, fc3_b, out, B);
}

// Round 7
// 131.072 us; speedup vs baseline: 1.6643x; 1.6643x over previous
//
#include <hip/hip_runtime.h>
#include <hip/hip_fp16.h>
#include <math.h>

#define PI_D 3.141592653589793

typedef _Float16 h2 __attribute__((ext_vector_type(2)));
typedef _Float16 h4 __attribute__((ext_vector_type(4)));
typedef _Float16 h8 __attribute__((ext_vector_type(8)));
typedef unsigned short us8 __attribute__((ext_vector_type(8)));
typedef __fp16 f16v2 __attribute__((ext_vector_type(2)));
typedef __fp16 f16v8 __attribute__((ext_vector_type(8)));
typedef float f32x4 __attribute__((ext_vector_type(4)));

#define STR1 264     // gl1h/gr1h row stride in halves (528 B; 33 h8)
#define STR2H 72     // gl2h/gr2h fp16 row stride in halves (144 B)

#define SV(v, a, b) __builtin_shufflevector(v, v, a, b)

static __device__ __forceinline__ h2 pack_h2(float a, float b) {
    return __builtin_bit_cast(h2, __builtin_amdgcn_cvt_pkrtz(a, b));
}

static __device__ __forceinline__ float fdot2(h2 a, h2 b, float c) {
    return __builtin_amdgcn_fdot2(__builtin_bit_cast(f16v2, a),
                                  __builtin_bit_cast(f16v2, b), c, false);
}

static __device__ __forceinline__ h8 habs8(h8 x) {
    us8 u = __builtin_bit_cast(us8, x);
    us8 m = {0x7fff, 0x7fff, 0x7fff, 0x7fff, 0x7fff, 0x7fff, 0x7fff, 0x7fff};
    return __builtin_bit_cast(h8, (us8)(u & m));
}

static __device__ __forceinline__ f32x4 mfma16(h8 a, h8 b, f32x4 c) {
    return __builtin_amdgcn_mfma_f32_16x16x32_f16(
        __builtin_bit_cast(f16v8, a), __builtin_bit_cast(f16v8, b), c, 0, 0, 0);
}

// 512 threads (8 waves) per sample, grid = B.
// __launch_bounds__(512, 4): the COMPILER caps VGPR at 64 under this (its
// occupancy accounting is 2x conservative vs HW: R5 (256,4)->64 VGPR,
// R6 (512,8)->32 VGPR + 426 MB scratch spill = the regression).
// At 64 VGPR actual, HARDWARE schedules 8 waves/SIMD; LDS 37.4 KB * 4
// blocks = 149.5 KB <= 160 KB -> 32 waves/CU resident (was 16 in R5).
// logits1 drops the gl-row register cache (-32 VGPR pressure) to
// guarantee no spill under the 64 cap; LDS re-reads are not a bottleneck
// (R0->R2 A/B was neutral).
__global__ __launch_bounds__(512, 4) void actor_fused_kernel(
    const float* __restrict__ state24,
    const float* __restrict__ Wl1, const float* __restrict__ Wr1,
    const float* __restrict__ att1, const float* __restrict__ b1,
    const float* __restrict__ Wl2, const float* __restrict__ Wr2,
    const float* __restrict__ att2, const float* __restrict__ b2,
    const float* __restrict__ fc1_w, const float* __restrict__ fc1_b,
    const float* __restrict__ fc2_w, const float* __restrict__ fc2_b,
    const float* __restrict__ fc3_w, const float* __restrict__ fc3_b,
    float* __restrict__ out, int B)
{
    const int smp = blockIdx.x;
    const int tid = threadIdx.x;
    const int wid = tid >> 6;        // 0..7
    const int lane = tid & 63;

    __shared__ float sinL[20], cosL[20], laserL[20], robotL[4];
    __shared__ __align__(16) h2 attLh[128];
    __shared__ __align__(16) h2 att2Lh[32];
    __shared__ __align__(16) _Float16 gr1h[22 * STR1];
    __shared__ __align__(16) union {
        struct { _Float16 gl1h[22 * STR1];
                 float ePf[128 * 24];
                 float uv[168]; } p1;
        struct { _Float16 gl2h[21 * STR2H];
                 _Float16 gr2h[21 * STR2H];
                 _Float16 gl2hT[64 * 32];
                 float e2[32 * 24];
                 float u2v2[42];
                 float red[8][256];
                 _Float16 nfvh[64]; _Float16 hah[256]; _Float16 hbh[256]; } p2;
    } U;

    // ---- setup ----
    if (tid < 20) {
        double step = (PI_D + 0.03) / 20.0;
        float bound = (float)(-PI_D / 2.0 - 0.03 + (double)tid * step);
        float ang = bound + (float)(PI_D / 20.0);
        sinL[tid] = sinf(ang);
        cosL[tid] = cosf(ang);
        laserL[tid] = state24[smp * 24 + tid] * 0.1f;
    }
    if (tid >= 32 && tid < 36) {
        int q = tid - 32;
        robotL[q] = state24[smp * 24 + 20 + q];
    }
    if (tid < 128) {
        float2 ap = ((const float2*)att1)[tid];
        attLh[tid] = pack_h2(0.4f * ap.x, 0.4f * ap.y);
    }
    if (tid >= 128 && tid < 160) {
        float2 ap = ((const float2*)att2)[tid - 128];
        att2Lh[tid - 128] = pack_h2(0.4f * ap.x, 0.4f * ap.y);
    }
    __syncthreads();

    // ---- transform1: 512 threads = 128 h2-cols x 4 node-quarters ----
    {
        const int d2 = tid & 127;
        const int qtr = tid >> 7;        // 0..3: nodes qtr*6 .. qtr*6+5 (qtr3: 3)
        float2 wl[7], wr[7];
        #pragma unroll
        for (int k = 0; k < 7; k++) {
            wl[k] = ((const float2*)Wl1)[k * 128 + d2];
            wr[k] = ((const float2*)Wr1)[k * 128 + d2];
        }
        if (qtr == 0) {
            h2 zz2 = {};
            ((h2*)(U.p1.gl1h + 21 * STR1))[d2] = zz2;
            ((h2*)(gr1h + 21 * STR1))[d2] = zz2;
        }
        const int base = qtr * 6;
        #pragma unroll
        for (int nn = 0; nn < 6; ++nn) {
            int node = base + nn;
            if (node < 21) {
                float a0, a1, b0, b1v;
                if (node < 20) {
                    float l = laserL[node], sv = sinL[node], c = cosL[node];
                    a0 = l * wl[0].x + sv * wl[1].x + c * wl[2].x;
                    a1 = l * wl[0].y + sv * wl[1].y + c * wl[2].y;
                    b0 = l * wr[0].x + sv * wr[1].x + c * wr[2].x;
                    b1v = l * wr[0].y + sv * wr[1].y + c * wr[2].y;
                } else {
                    float r0 = robotL[0], r1 = robotL[1], r2 = robotL[2], r3 = robotL[3];
                    a0 = r0 * wl[3].x + r1 * wl[4].x + r2 * wl[5].x + r3 * wl[6].x;
                    a1 = r0 * wl[3].y + r1 * wl[4].y + r2 * wl[5].y + r3 * wl[6].y;
                    b0 = r0 * wr[3].x + r1 * wr[4].x + r2 * wr[5].x + r3 * wr[6].x;
                    b1v = r0 * wr[3].y + r1 * wr[4].y + r2 * wr[5].y + r3 * wr[6].y;
                }
                ((h2*)(U.p1.gl1h + node * STR1))[d2] = pack_h2(a0, a1);
                ((h2*)(gr1h + node * STR1))[d2] = pack_h2(b0, b1v);
            }
        }
    }
    __syncthreads();

    // ---- logits1: wave pair (2h, 2h+1) covers head h; p = pair-index 0..127
    //      = (j, 4-wide i-strip); rows read from LDS (no reg cache) ----
    {
        const int h = wid >> 1;
        const int p = (wid & 1) * 64 + lane;       // 0..127
        h2 ar[32];
        #pragma unroll
        for (int q = 0; q < 32; ++q) ar[q] = attLh[h * 32 + q];

        const bool act = p < 126;
        const int jn  = act ? p % 21 : 0;
        const int seg = act ? p / 21 : 0;          // 0..5

        const h8* gA8 = (const h8*)(U.p1.gl1h + jn * STR1 + h * 64);

        if (act && seg == 0) {                     // u_j (p = 0..20)
            float l0 = 0.f, l1 = 0.f;
            #pragma unroll
            for (int ch = 0; ch < 8; ++ch) {
                h8 g = gA8[ch];
                l0 = fdot2(SV(g, 0, 1), ar[ch * 4 + 0], l0);
                l1 = fdot2(SV(g, 2, 3), ar[ch * 4 + 1], l1);
                l0 = fdot2(SV(g, 4, 5), ar[ch * 4 + 2], l0);
                l1 = fdot2(SV(g, 6, 7), ar[ch * 4 + 3], l1);
            }
            U.p1.uv[h * 21 + jn] = l0 + l1;
        }

        #pragma unroll
        for (int t = 0; t < 4; ++t) {
            const int i = seg * 4 + t;             // 0..23, guard <21
            if (i < 21) {
                const h8* gB8 = (const h8*)(gr1h + i * STR1 + h * 64);
                float m0 = 0.f, m1 = 0.f;
                #pragma unroll
                for (int ch = 0; ch < 8; ++ch) {
                    h8 x = gA8[ch] + gB8[ch];
                    h8 ax = habs8(x);
                    m0 = fdot2(SV(ax, 0, 1), ar[ch * 4 + 0], m0);
                    m1 = fdot2(SV(ax, 2, 3), ar[ch * 4 + 1], m1);
                    m0 = fdot2(SV(ax, 4, 5), ar[ch * 4 + 2], m0);
                    m1 = fdot2(SV(ax, 6, 7), ar[ch * 4 + 3], m1);
                }
                if (act) U.p1.ePf[(h * 32 + i) * 24 + jn] = m0 + m1;
            }
        }

        if (p >= 21 && p < 42) {                   // v_i (sub0 lanes 21..41)
            const int idx = p - 21;
            const h8* row8 = (const h8*)(gr1h + idx * STR1 + h * 64);
            float l0 = 0.f, l1 = 0.f;
            #pragma unroll
            for (int ch = 0; ch < 8; ++ch) {
                h8 g = row8[ch];
                l0 = fdot2(SV(g, 0, 1), ar[ch * 4 + 0], l0);
                l1 = fdot2(SV(g, 2, 3), ar[ch * 4 + 1], l1);
                l0 = fdot2(SV(g, 4, 5), ar[ch * 4 + 2], l0);
                l1 = fdot2(SV(g, 6, 7), ar[ch * 4 + 3], l1);
            }
            U.p1.uv[84 + h * 21 + idx] = l0 + l1;
        }
    }
    __syncthreads();

    // ---- softmax1: wave pair per head; sub0 rows 0..10, sub1 rows 11..20 ----
    {
        const int h = wid >> 1;
        const int sub = wid & 1;
        if (lane < 11 - sub) {
            int i = sub * 11 + lane;
            int r = h * 32 + i;
            float* row = U.p1.ePf + r * 24;
            const float* uu = U.p1.uv + h * 21;
            float vi = 1.5f * U.p1.uv[84 + h * 21 + i];
            float ebuf[21];
            float m = -1e30f;
            #pragma unroll
            for (int j = 0; j < 21; j++) {
                float e = row[j] + 1.5f * uu[j] + vi;
                ebuf[j] = e;
                m = fmaxf(m, e);
            }
            float sum = 0.f;
            #pragma unroll
            for (int j = 0; j < 21; j++) { float v = __expf(ebuf[j] - m); ebuf[j] = v; sum += v; }
            float rinv = 1.f / sum;
            h8* hp8 = (h8*)(U.p1.ePf) + r * 6;
            h8 o0, o1, o2;
            #pragma unroll
            for (int q = 0; q < 8; ++q) o0[q] = (_Float16)(ebuf[q] * rinv);
            #pragma unroll
            for (int q = 0; q < 8; ++q) o1[q] = (_Float16)(ebuf[8 + q] * rinv);
            #pragma unroll
            for (int q = 0; q < 5; ++q) o2[q] = (_Float16)(ebuf[16 + q] * rinv);
            o2[5] = (_Float16)0.f; o2[6] = (_Float16)0.f; o2[7] = (_Float16)0.f;
            h8 zz = {};
            hp8[0] = o0; hp8[1] = o1; hp8[2] = o2;
            hp8[3] = zz; hp8[4] = zz; hp8[5] = zz;
        }
        {   // zero fp16 A-frag rows (h, 21..31): 66 h8 over the wave pair
            int z = sub * 64 + lane;
            if (z < 66) {
                int rr = z / 6, slot = z - rr * 6;
                h8 zz = {};
                ((h8*)U.p1.ePf)[(h * 32 + 21 + rr) * 6 + slot] = zz;
            }
        }
    }
    __syncthreads();

    // ---- agg1 via MFMA: wave pair per head; sub = A0/A1 row-half ----
    {
        const int h = wid >> 1;
        const int sub = wid & 1;
        const int mcol = lane & 15;
        const int quad = lane >> 4;
        const h8* Af = (const h8*)U.p1.ePf;
        h8 A = Af[(h * 32 + sub * 16 + mcol) * 6 + quad];   // rows>=21 are zeros
        int rowoff[8];
        #pragma unroll
        for (int jj = 0; jj < 8; ++jj) {
            int rr = quad * 8 + jj;
            rowoff[jj] = (rr > 21 ? 21 : rr) * STR1;
        }
        const int colbase = h * 64 + mcol;
        f32x4 z4 = {0.f, 0.f, 0.f, 0.f};
        #pragma unroll
        for (int t = 0; t < 4; ++t) {
            int col = colbase + t * 16;
            float bb = b1[col];
            h8 bv;
            #pragma unroll
            for (int jj = 0; jj < 8; ++jj) bv[jj] = U.p1.gl1h[rowoff[jj] + col];
            f32x4 d = mfma16(A, bv, z4);
            #pragma unroll
            for (int r = 0; r < 4; ++r) {
                int n = sub * 16 + quad * 4 + r;
                if (n < 21) {
                    float v = d[r] + bb;
                    v = v > 0.f ? v : __expf(v) - 1.f;
                    gr1h[n * STR1 + col] = (_Float16)v;
                }
            }
        }
    }
    __syncthreads();

    // ---- layer-2 transforms via MFMA: 8 waves = 4 ntiles x 2 row-halves;
    //      B-frags converted inline from fp32 (RNE, same layout as before) ----
    {
        const int ntile = wid >> 1;      // 0..3
        const int rhalf = wid & 1;
        const int mrow = lane & 15;
        const int quad = lane >> 4;
        int arow = rhalf ? (16 + mrow > 21 ? 21 : 16 + mrow) : mrow;
        const int ncol = ntile * 16 + mrow;
        const float* pL = Wl2 + ncol;
        const float* pR = Wr2 + ncol;
        f32x4 aL = {0.f, 0.f, 0.f, 0.f}, aR = {0.f, 0.f, 0.f, 0.f};
        #pragma unroll
        for (int kc = 0; kc < 8; ++kc) {
            const int kb = kc * 32 + quad * 8;
            h8 BL, BR;
            #pragma unroll
            for (int j = 0; j < 8; ++j) {
                BL[j] = (_Float16)pL[(kb + j) * 64];
                BR[j] = (_Float16)pR[(kb + j) * 64];
            }
            h8 A = *(const h8*)(gr1h + arow * STR1 + quad * 8 + kc * 32);
            aL = mfma16(A, BL, aL);
            aR = mfma16(A, BR, aR);
        }
        const int col = ncol;
        #pragma unroll
        for (int r = 0; r < 4; ++r) {
            int row = rhalf * 16 + quad * 4 + r;
            if (row < 21) {
                U.p2.gl2h[row * STR2H + col] = (_Float16)aL[r];
                U.p2.gr2h[row * STR2H + col] = (_Float16)aR[r];
            }
        }
        h2 lo = pack_h2(aL[0], aL[1]);
        h2 hi = pack_h2(aL[2], aL[3]);
        h4 pq = __builtin_shufflevector(lo, hi, 0, 1, 2, 3);
        *(h4*)(U.p2.gl2hT + col * 32 + rhalf * 16 + quad * 4) = pq;  // rows>=21 are zeros
    }
    __syncthreads();

    // ---- layer-2 logits: 1 duty per thread (441 pairs + 21 u2 + 21 v2) ----
    {
        h2 ar2[32];
        #pragma unroll
        for (int q = 0; q < 32; ++q) ar2[q] = att2Lh[q];

        const int p = tid;
        if (p < 441) {
            const int i = p / 21;
            const int jn = p - i * 21;
            const h8* gA8 = (const h8*)(U.p2.gl2h + jn * STR2H);
            const h8* gB8 = (const h8*)(U.p2.gr2h + i * STR2H);
            float m0 = 0.f, m1 = 0.f;
            #pragma unroll
            for (int ch = 0; ch < 8; ++ch) {
                h8 x = gA8[ch] + gB8[ch];
                h8 ax = habs8(x);
                m0 = fdot2(SV(ax, 0, 1), ar2[ch * 4 + 0], m0);
                m1 = fdot2(SV(ax, 2, 3), ar2[ch * 4 + 1], m1);
                m0 = fdot2(SV(ax, 4, 5), ar2[ch * 4 + 2], m0);
                m1 = fdot2(SV(ax, 6, 7), ar2[ch * 4 + 3], m1);
            }
            U.p2.e2[i * 24 + jn] = m0 + m1;
        } else if (p < 483) {
            const int isV = p >= 462;
            const int j = p - (isV ? 462 : 441);
            const h8* row8 = (const h8*)((isV ? U.p2.gr2h : U.p2.gl2h) + j * STR2H);
            float l0 = 0.f, l1 = 0.f;
            #pragma unroll
            for (int ch = 0; ch < 8; ++ch) {
                h8 g = row8[ch];
                l0 = fdot2(SV(g, 0, 1), ar2[ch * 4 + 0], l0);
                l1 = fdot2(SV(g, 2, 3), ar2[ch * 4 + 1], l1);
                l0 = fdot2(SV(g, 4, 5), ar2[ch * 4 + 2], l0);
                l1 = fdot2(SV(g, 6, 7), ar2[ch * 4 + 3], l1);
            }
            U.p2.u2v2[isV * 21 + j] = l0 + l1;
        }
    }
    __syncthreads();

    // ---- softmax-2 ----
    if (tid < 21) {
        int i = tid;
        float* row = U.p2.e2 + i * 24;
        const float* uu = U.p2.u2v2;
        float vi = 1.5f * U.p2.u2v2[21 + i];
        float ebuf[21];
        float m = -1e30f;
        #pragma unroll
        for (int j = 0; j < 21; j++) {
            float e = row[j] + 1.5f * uu[j] + vi;
            ebuf[j] = e;
            m = fmaxf(m, e);
        }
        float sum = 0.f;
        #pragma unroll
        for (int j = 0; j < 21; j++) { float v = __expf(ebuf[j] - m); ebuf[j] = v; sum += v; }
        float rinv = 1.f / sum;
        h8* hp8 = (h8*)(U.p2.e2) + i * 6;
        h8 o0, o1, o2;
        #pragma unroll
        for (int q = 0; q < 8; ++q) o0[q] = (_Float16)(ebuf[q] * rinv);
        #pragma unroll
        for (int q = 0; q < 8; ++q) o1[q] = (_Float16)(ebuf[8 + q] * rinv);
        #pragma unroll
        for (int q = 0; q < 5; ++q) o2[q] = (_Float16)(ebuf[16 + q] * rinv);
        o2[5] = (_Float16)0.f; o2[6] = (_Float16)0.f; o2[7] = (_Float16)0.f;
        h8 zz = {};
        hp8[0] = o0; hp8[1] = o1; hp8[2] = o2;
        hp8[3] = zz; hp8[4] = zz; hp8[5] = zz;
    } else if (tid < 87) {
        int z = tid - 21;                 // rows 21..31 x 6 slots
        int rr = z / 6, slot = z - rr * 6;
        h8 zz = {};
        ((h8*)U.p2.e2)[(21 + rr) * 6 + slot] = zz;
    }
    __syncthreads();

    // ---- agg2 + mean-pool via MFMA -> nfvh (waves 0..3) ----
    if (wid < 4) {
        const int mcol = lane & 15;
        const int quad = lane >> 4;
        const int col = wid * 16 + mcol;
        float bb = b2[col];
        f32x4 z4 = {0.f, 0.f, 0.f, 0.f};
        const h8* Af2 = (const h8*)U.p2.e2;
        h8 A0 = Af2[mcol * 6 + quad];
        h8 A1 = Af2[(16 + mcol) * 6 + quad];
        h8 bv = *(const h8*)(U.p2.gl2hT + col * 32 + quad * 8);
        f32x4 d0 = mfma16(A0, bv, z4);
        f32x4 d1 = mfma16(A1, bv, z4);
        float sum = (d0[0] + d0[1]) + (d0[2] + d0[3])
                  + (d1[0] + d1[1]) + (d1[2] + d1[3]);
        sum += __shfl_xor(sum, 16, 64);
        sum += __shfl_xor(sum, 32, 64);
        if (quad == 0) U.p2.nfvh[col] = (_Float16)(sum * (1.f / 21.f) + bb);
    }
    __syncthreads();

    // ---- FC1 (64 -> 256): fp32 weights direct, k split 8 ways ----
    {
        int c = tid & 63, g = tid >> 6;            // g 0..7
        const float4* W1 = (const float4*)fc1_w;   // [64 rows][64 float4]
        float4 acc = {0.f, 0.f, 0.f, 0.f};
        #pragma unroll
        for (int kk = 0; kk < 4; ++kk) {
            int k2 = g * 4 + kk;
            float4 r0 = W1[(2 * k2) * 64 + c];
            float4 r1 = W1[(2 * k2 + 1) * 64 + c];
            h2 x = ((const h2*)U.p2.nfvh)[k2];
            float x0 = (float)x[0], x1 = (float)x[1];
            acc.x = fmaf(r0.x, x0, fmaf(r1.x, x1, acc.x));
            acc.y = fmaf(r0.y, x0, fmaf(r1.y, x1, acc.y));
            acc.z = fmaf(r0.z, x0, fmaf(r1.z, x1, acc.z));
            acc.w = fmaf(r0.w, x0, fmaf(r1.w, x1, acc.w));
        }
        ((float4*)U.p2.red[g])[c] = acc;
    }
    __syncthreads();
    if (tid < 256) {
        float v = fc1_b[tid];
        #pragma unroll
        for (int g = 0; g < 8; ++g) v += U.p2.red[g][tid];
        U.p2.hah[tid] = (_Float16)fmaxf(v, 0.f);
    }
    __syncthreads();

    // ---- FC2 (256 -> 256): fp32 weights direct, k split 8 ways ----
    {
        int c = tid & 63, g = tid >> 6;
        const float4* W2 = (const float4*)fc2_w;   // [256 rows][64 float4]
        const h8* ha = (const h8*)U.p2.hah;
        float4 acc = {0.f, 0.f, 0.f, 0.f};
        #pragma unroll
        for (int q = 0; q < 4; ++q) {
            h8 xa = ha[g * 4 + q];
            #pragma unroll
            for (int pp = 0; pp < 4; ++pp) {
                int k2 = g * 16 + q * 4 + pp;
                float4 r0 = W2[(2 * k2) * 64 + c];
                float4 r1 = W2[(2 * k2 + 1) * 64 + c];
                float x0 = (float)xa[2 * pp], x1 = (float)xa[2 * pp + 1];
                acc.x = fmaf(r0.x, x0, fmaf(r1.x, x1, acc.x));
                acc.y = fmaf(r0.y, x0, fmaf(r1.y, x1, acc.y));
                acc.z = fmaf(r0.z, x0, fmaf(r1.z, x1, acc.z));
                acc.w = fmaf(r0.w, x0, fmaf(r1.w, x1, acc.w));
            }
        }
        ((float4*)U.p2.red[g])[c] = acc;
    }
    __syncthreads();
    if (tid < 256) {
        float v = fc2_b[tid];
        #pragma unroll
        for (int g = 0; g < 8; ++g) v += U.p2.red[g][tid];
        U.p2.hbh[tid] = (_Float16)fmaxf(v, 0.f);
    }
    __syncthreads();

    // ---- FC3 (256 -> 2) + tanh: waves 0,1 own outputs 0,1 ----
    {
        int g = tid >> 6;
        if (g < 2) {
            int o = g;
            int l = tid & 63;
            float sum = 0.f;
            #pragma unroll
            for (int m = 0; m < 4; m++) {
                int k = l + 64 * m;
                sum = fmaf((float)U.p2.hbh[k], fc3_w[k * 2 + o], sum);
            }
            #pragma unroll
            for (int off = 32; off >= 1; off >>= 1) sum += __shfl_down(sum, off, 64);
            if (l == 0) out[smp * 2 + o] = tanhf(sum + fc3_b[o]);
        }
    }
}

extern "C" void kernel_launch(void* const* d_in, const int* in_sizes, int n_in,
                              void* d_out, int out_size, void* d_ws, size_t ws_size,
                              hipStream_t stream) {
    const float* state24 = (const float*)d_in[0];
    const float* Wl1 = (const float*)d_in[1];
    const float* Wr1 = (const float*)d_in[2];
    const float* att1 = (const float*)d_in[3];
    const float* b1 = (const float*)d_in[4];
    const float* Wl2 = (const float*)d_in[5];
    const float* Wr2 = (const float*)d_in[6];
    const float* att2 = (const float*)d_in[7];
    const float* b2 = (const float*)d_in[8];
    const float* fc1_w = (const float*)d_in[9];
    const float* fc1_b = (const float*)d_in[10];
    const float* fc2_w = (const float*)d_in[11];
    const float* fc2_b = (const float*)d_in[12];
    const float* fc3_w = (const float*)d_in[13];
    const float* fc3_b = (const float*)d_in[14];
    float* out = (float*)d_out;

    (void)d_ws; (void)ws_size;          // single-dispatch: no workspace needed

    int B = in_sizes[0] / 24;
    actor_fused_kernel<<<B, 512, 0, stream>>>(
        state24, Wl1, Wr1, att1, b1, Wl2, Wr2, att2, b2,
        fc1_w, fc1_b, fc2_w, fc2_b, fc3_w, fc3_b, out, B);
}

// Round 8
// 111.077 us; speedup vs baseline: 1.9638x; 1.1800x over previous
//
#include <hip/hip_runtime.h>
#include <hip/hip_fp16.h>
#include <math.h>

#define PI_D 3.141592653589793

typedef _Float16 h2 __attribute__((ext_vector_type(2)));
typedef _Float16 h4 __attribute__((ext_vector_type(4)));
typedef _Float16 h8 __attribute__((ext_vector_type(8)));
typedef unsigned short us8 __attribute__((ext_vector_type(8)));
typedef __fp16 f16v2 __attribute__((ext_vector_type(2)));
typedef __fp16 f16v8 __attribute__((ext_vector_type(8)));
typedef float f32x4 __attribute__((ext_vector_type(4)));

#define STR1 264     // gl1h/gr1h row stride in halves (528 B; 33 h8)
#define STR2H 72     // gl2h/gr2h fp16 row stride in halves (144 B)

#define SV(v, a, b) __builtin_shufflevector(v, v, a, b)

static __device__ __forceinline__ h2 pack_h2(float a, float b) {
    return __builtin_bit_cast(h2, __builtin_amdgcn_cvt_pkrtz(a, b));
}

static __device__ __forceinline__ float fdot2(h2 a, h2 b, float c) {
    return __builtin_amdgcn_fdot2(__builtin_bit_cast(f16v2, a),
                                  __builtin_bit_cast(f16v2, b), c, false);
}

static __device__ __forceinline__ h8 habs8(h8 x) {
    us8 u = __builtin_bit_cast(us8, x);
    us8 m = {0x7fff, 0x7fff, 0x7fff, 0x7fff, 0x7fff, 0x7fff, 0x7fff, 0x7fff};
    return __builtin_bit_cast(h8, (us8)(u & m));
}

static __device__ __forceinline__ f32x4 mfma16(h8 a, h8 b, f32x4 c) {
    return __builtin_amdgcn_mfma_f32_16x16x32_f16(
        __builtin_bit_cast(f16v8, a), __builtin_bit_cast(f16v8, b), c, 0, 0, 0);
}

static __device__ __forceinline__ void wave_fence() {
    asm volatile("" ::: "memory");
#if __has_builtin(__builtin_amdgcn_wave_barrier)
    __builtin_amdgcn_wave_barrier();
#endif
    asm volatile("" ::: "memory");
}

// ---- pre-pass: pack weights to fp16 (round-10 layouts) ----
__global__ __launch_bounds__(256) void pack_weights_kernel(
    const float* __restrict__ Wl2, const float* __restrict__ Wr2,
    const float* __restrict__ fc1_w, const float* __restrict__ fc2_w,
    h8* __restrict__ ws)
{
    int idx = blockIdx.x * 256 + threadIdx.x;
    if (idx < 4096) {
        const float* W = idx < 2048 ? Wl2 : Wr2;
        int t = idx & 2047;
        int ntile = t >> 9, rem = t & 511;
        int kchunk = rem >> 6, lane = rem & 63;
        int n = ntile * 16 + (lane & 15);
        int k0 = kchunk * 32 + (lane >> 4) * 8;
        h8 o;
        #pragma unroll
        for (int j = 0; j < 8; ++j) o[j] = (_Float16)W[(k0 + j) * 64 + n];
        ws[idx] = o;
    } else if (idx < 6144) {
        int t = idx - 4096;
        int k2 = t >> 6, c = t & 63;
        h8 o;
        #pragma unroll
        for (int q = 0; q < 4; ++q) {
            o[2 * q]     = (_Float16)fc1_w[(2 * k2) * 256 + 4 * c + q];
            o[2 * q + 1] = (_Float16)fc1_w[(2 * k2 + 1) * 256 + 4 * c + q];
        }
        ws[idx] = o;
    } else {
        int t = idx - 6144;
        int k2 = t >> 6, c = t & 63;
        h8 o;
        #pragma unroll
        for (int q = 0; q < 4; ++q) {
            o[2 * q]     = (_Float16)fc2_w[(2 * k2) * 256 + 4 * c + q];
            o[2 * q + 1] = (_Float16)fc2_w[(2 * k2 + 1) * 256 + 4 * c + q];
        }
        ws[idx] = o;
    }
}

__global__ __launch_bounds__(256, 2) void actor_fused_kernel(
    const float* __restrict__ state24,
    const float* __restrict__ Wl1, const float* __restrict__ Wr1,
    const float* __restrict__ att1, const float* __restrict__ b1,
    const float* __restrict__ att2, const float* __restrict__ b2,
    const float* __restrict__ fc1_b, const float* __restrict__ fc2_b,
    const float* __restrict__ fc3_w, const float* __restrict__ fc3_b,
    const h8* __restrict__ wsL, const h8* __restrict__ wsR,
    const h8* __restrict__ wsF1, const h8* __restrict__ wsF2,
    float* __restrict__ out, int B)
{
    const int bix = blockIdx.x;
    const int tid = threadIdx.x;
    const int smp0 = 2 * bix;
    if (smp0 >= B) return;
    const int smp1 = (smp0 + 1 < B) ? smp0 + 1 : smp0;

    __shared__ float sinL[20], cosL[20], laserL[2][20], robotL[2][4];
    __shared__ __align__(16) h2 attLh[128];
    __shared__ __align__(16) h2 att2Lh[32];
    __shared__ __align__(16) _Float16 gr1h[2][22 * STR1];
    __shared__ __align__(16) union {
        struct { _Float16 gl1h[2][22 * STR1];
                 float ePf[2][128 * 24];
                 float uv[2][168]; } p1;
        struct { _Float16 gl2h[2][21 * STR2H];
                 _Float16 gr2h[2][21 * STR2H];
                 _Float16 gl2hT[2][64 * 32];
                 float e2[2][32 * 24];
                 float u2v2[2][42];
                 float red[2][4][256];
                 _Float16 nfvh[2][64]; _Float16 hah[2][256]; _Float16 hbh[2][256]; } p2;
    } U;

    // ---- setup ----
    if (tid < 20) {
        double step = (PI_D + 0.03) / 20.0;
        float bound = (float)(-PI_D / 2.0 - 0.03 + (double)tid * step);
        float ang = bound + (float)(PI_D / 20.0);
        sinL[tid] = sinf(ang);
        cosL[tid] = cosf(ang);
        laserL[0][tid] = state24[smp0 * 24 + tid] * 0.1f;
        laserL[1][tid] = state24[smp1 * 24 + tid] * 0.1f;
    }
    if (tid >= 32 && tid < 40) {
        int s = (tid - 32) >> 2, q = (tid - 32) & 3;
        robotL[s][q] = state24[(s ? smp1 : smp0) * 24 + 20 + q];
    }
    if (tid < 128) {
        float2 ap = ((const float2*)att1)[tid];
        attLh[tid] = pack_h2(0.4f * ap.x, 0.4f * ap.y);
    }
    if (tid >= 128 && tid < 160) {
        float2 ap = ((const float2*)att2)[tid - 128];
        att2Lh[tid - 128] = pack_h2(0.4f * ap.x, 0.4f * ap.y);
    }
    __syncthreads();

    // ================= L1 block: wave h owns head h, both samples =================
    {
        const int h = tid >> 6;
        const int lane = tid & 63;

        // ---- transform1: weights loaded once, used for both samples ----
        {
            const int cp = lane & 31;
            const int half = lane >> 5;
            const int d2 = h * 32 + cp;
            float2 wl[7], wr[7];
            #pragma unroll
            for (int k = 0; k < 7; k++) {
                wl[k] = ((const float2*)Wl1)[k * 128 + d2];
                wr[k] = ((const float2*)Wr1)[k * 128 + d2];
            }
            if (half == 0) {
                h2 zz2 = {};
                #pragma unroll
                for (int s = 0; s < 2; ++s) {
                    ((h2*)(U.p1.gl1h[s] + 21 * STR1))[d2] = zz2;
                    ((h2*)(gr1h[s] + 21 * STR1))[d2] = zz2;
                }
            }
            const int base = half * 11;
            #pragma unroll
            for (int nn = 0; nn < 11; ++nn) {
                int node = base + nn;
                if (node < 21) {
                    #pragma unroll
                    for (int s = 0; s < 2; ++s) {
                        float a0, a1, b0, b1v;
                        if (node < 20) {
                            float l = laserL[s][node], sv = sinL[node], c = cosL[node];
                            a0 = l * wl[0].x + sv * wl[1].x + c * wl[2].x;
                            a1 = l * wl[0].y + sv * wl[1].y + c * wl[2].y;
                            b0 = l * wr[0].x + sv * wr[1].x + c * wr[2].x;
                            b1v = l * wr[0].y + sv * wr[1].y + c * wr[2].y;
                        } else {
                            float r0 = robotL[s][0], r1 = robotL[s][1], r2 = robotL[s][2], r3 = robotL[s][3];
                            a0 = r0 * wl[3].x + r1 * wl[4].x + r2 * wl[5].x + r3 * wl[6].x;
                            a1 = r0 * wl[3].y + r1 * wl[4].y + r2 * wl[5].y + r3 * wl[6].y;
                            b0 = r0 * wr[3].x + r1 * wr[4].x + r2 * wr[5].x + r3 * wr[6].x;
                            b1v = r0 * wr[3].y + r1 * wr[4].y + r2 * wr[5].y + r3 * wr[6].y;
                        }
                        ((h2*)(U.p1.gl1h[s] + node * STR1))[d2] = pack_h2(a0, a1);
                        ((h2*)(gr1h[s] + node * STR1))[d2] = pack_h2(b0, b1v);
                    }
                }
            }
        }
        wave_fence();

        // ---- logits1 (abs part) + u/v, both samples ----
        {
            h2 ar[32];
            #pragma unroll
            for (int q = 0; q < 32; ++q) ar[q] = attLh[h * 32 + q];

            #pragma unroll
            for (int s = 0; s < 2; ++s) {
                for (int it = 0; it < 7; ++it) {
                    int q = it * 64 + lane;
                    if (q < 441) {
                        int i = q / 21;
                        int j = q - i * 21;
                        const h8* gA8 = (const h8*)(U.p1.gl1h[s] + j * STR1 + h * 64);
                        const h8* gB8 = (const h8*)(gr1h[s] + i * STR1 + h * 64);
                        float m0 = 0.f, m1 = 0.f;
                        #pragma unroll
                        for (int ch = 0; ch < 8; ++ch) {
                            h8 x = gA8[ch] + gB8[ch];
                            h8 ax = habs8(x);
                            m0 = fdot2(SV(ax, 0, 1), ar[ch * 4 + 0], m0);
                            m1 = fdot2(SV(ax, 2, 3), ar[ch * 4 + 1], m1);
                            m0 = fdot2(SV(ax, 4, 5), ar[ch * 4 + 2], m0);
                            m1 = fdot2(SV(ax, 6, 7), ar[ch * 4 + 3], m1);
                        }
                        U.p1.ePf[s][(h * 32 + i) * 24 + j] = m0 + m1;
                    }
                }
            }
            if (lane < 42) {
                int isV = lane >= 21;
                int idx = isV ? lane - 21 : lane;
                #pragma unroll
                for (int s = 0; s < 2; ++s) {
                    const _Float16* rowp = (isV ? (const _Float16*)gr1h[s]
                                                : (const _Float16*)U.p1.gl1h[s]) + idx * STR1 + h * 64;
                    const h8* row8 = (const h8*)rowp;
                    float l0 = 0.f, l1 = 0.f;
                    #pragma unroll
                    for (int ch = 0; ch < 8; ++ch) {
                        h8 g = row8[ch];
                        l0 = fdot2(SV(g, 0, 1), ar[ch * 4 + 0], l0);
                        l1 = fdot2(SV(g, 2, 3), ar[ch * 4 + 1], l1);
                        l0 = fdot2(SV(g, 4, 5), ar[ch * 4 + 2], l0);
                        l1 = fdot2(SV(g, 6, 7), ar[ch * 4 + 3], l1);
                    }
                    U.p1.uv[s][(isV ? 84 : 0) + h * 21 + idx] = l0 + l1;
                }
            }
        }
        wave_fence();

        // ---- softmax1: lanes 0..20 s=0, 21..41 s=1; zero rows 21..31 both samples ----
        if (lane < 42) {
            int s = lane >= 21;
            int i = lane - s * 21;
            int r = h * 32 + i;
            float* row = U.p1.ePf[s] + r * 24;
            const float* uu = U.p1.uv[s] + h * 21;
            float vi = 1.5f * U.p1.uv[s][84 + h * 21 + i];
            float ebuf[21];
            float m = -1e30f;
            #pragma unroll
            for (int j = 0; j < 21; j++) {
                float e = row[j] + 1.5f * uu[j] + vi;
                ebuf[j] = e;
                m = fmaxf(m, e);
            }
            float sum = 0.f;
            #pragma unroll
            for (int j = 0; j < 21; j++) { float v = __expf(ebuf[j] - m); ebuf[j] = v; sum += v; }
            float rinv = 1.f / sum;
            h8* hp8 = (h8*)(U.p1.ePf[s]) + r * 6;
            h8 o0, o1, o2;
            #pragma unroll
            for (int q = 0; q < 8; ++q) o0[q] = (_Float16)(ebuf[q] * rinv);
            #pragma unroll
            for (int q = 0; q < 8; ++q) o1[q] = (_Float16)(ebuf[8 + q] * rinv);
            #pragma unroll
            for (int q = 0; q < 5; ++q) o2[q] = (_Float16)(ebuf[16 + q] * rinv);
            o2[5] = (_Float16)0.f; o2[6] = (_Float16)0.f; o2[7] = (_Float16)0.f;
            h8 zz = {};
            hp8[0] = o0; hp8[1] = o1; hp8[2] = o2;
            hp8[3] = zz; hp8[4] = zz; hp8[5] = zz;
        }
        {   // zero fp16 A-frag rows (h, 21..31) x 2 samples: 132 h8 slots
            h8 zz = {};
            for (int z = lane; z < 132; z += 64) {
                int s = z >= 66;
                int zz2 = z - s * 66;
                int rr = zz2 / 6, slot = zz2 - rr * 6;
                ((h8*)U.p1.ePf[s])[(h * 32 + 21 + rr) * 6 + slot] = zz;
            }
        }
        wave_fence();

        // ---- agg1 via MFMA, both samples; bias loaded once ----
        {
            const int mcol = lane & 15;
            const int quad = lane >> 4;
            h8 A0s[2], A1s[2];
            #pragma unroll
            for (int s = 0; s < 2; ++s) {
                const h8* Af = (const h8*)U.p1.ePf[s];
                A0s[s] = Af[(h * 32 + mcol) * 6 + quad];
                A1s[s] = Af[(h * 32 + 16 + mcol) * 6 + quad];
            }
            int rowoff[8];
            #pragma unroll
            for (int jj = 0; jj < 8; ++jj) {
                int rr = quad * 8 + jj;
                rowoff[jj] = (rr > 21 ? 21 : rr) * STR1;
            }
            const int colbase = h * 64 + mcol;
            f32x4 z4 = {0.f, 0.f, 0.f, 0.f};
            #pragma unroll
            for (int t = 0; t < 4; ++t) {
                int col = colbase + t * 16;
                float bb = b1[col];
                #pragma unroll
                for (int s = 0; s < 2; ++s) {
                    h8 bv;
                    #pragma unroll
                    for (int jj = 0; jj < 8; ++jj) bv[jj] = U.p1.gl1h[s][rowoff[jj] + col];
                    f32x4 d0 = mfma16(A0s[s], bv, z4);
                    f32x4 d1 = mfma16(A1s[s], bv, z4);
                    #pragma unroll
                    for (int r = 0; r < 4; ++r) {
                        int n0 = quad * 4 + r;
                        float v = d0[r] + bb;
                        v = v > 0.f ? v : __expf(v) - 1.f;
                        gr1h[s][n0 * STR1 + col] = (_Float16)v;
                        int n1 = 16 + quad * 4 + r;
                        if (n1 < 21) {
                            float w2 = d1[r] + bb;
                            w2 = w2 > 0.f ? w2 : __expf(w2) - 1.f;
                            gr1h[s][n1 * STR1 + col] = (_Float16)w2;
                        }
                    }
                }
            }
        }
    }
    __syncthreads();
    // ================= end L1 block =================

    // ---- layer-2 transforms via MFMA; B-frags loaded once per kc, used by both samples ----
    {
        const int lane = tid & 63;
        const int w = tid >> 6;
        const int mrow = lane & 15;
        const int quad = lane >> 4;
        int rowA1 = 16 + mrow; if (rowA1 > 21) rowA1 = 21;
        const h8* bL = wsL + w * 512 + lane;
        const h8* bR = wsR + w * 512 + lane;
        f32x4 aL0[2], aL1[2], aR0[2], aR1[2];
        #pragma unroll
        for (int s = 0; s < 2; ++s) {
            aL0[s] = (f32x4){0.f, 0.f, 0.f, 0.f}; aL1[s] = (f32x4){0.f, 0.f, 0.f, 0.f};
            aR0[s] = (f32x4){0.f, 0.f, 0.f, 0.f}; aR1[s] = (f32x4){0.f, 0.f, 0.f, 0.f};
        }
        #pragma unroll
        for (int kc = 0; kc < 8; ++kc) {
            h8 BL = bL[kc * 64];
            h8 BR = bR[kc * 64];
            #pragma unroll
            for (int s = 0; s < 2; ++s) {
                h8 A0 = *(const h8*)(gr1h[s] + mrow * STR1 + quad * 8 + kc * 32);
                h8 A1 = *(const h8*)(gr1h[s] + rowA1 * STR1 + quad * 8 + kc * 32);
                aL0[s] = mfma16(A0, BL, aL0[s]);
                aL1[s] = mfma16(A1, BL, aL1[s]);
                aR0[s] = mfma16(A0, BR, aR0[s]);
                aR1[s] = mfma16(A1, BR, aR1[s]);
            }
        }
        const int col = w * 16 + mrow;
        #pragma unroll
        for (int s = 0; s < 2; ++s) {
            #pragma unroll
            for (int r = 0; r < 4; ++r) {
                int row0 = quad * 4 + r;
                U.p2.gl2h[s][row0 * STR2H + col] = (_Float16)aL0[s][r];
                U.p2.gr2h[s][row0 * STR2H + col] = (_Float16)aR0[s][r];
                int row1 = 16 + row0;
                if (row1 < 21) {
                    U.p2.gl2h[s][row1 * STR2H + col] = (_Float16)aL1[s][r];
                    U.p2.gr2h[s][row1 * STR2H + col] = (_Float16)aR1[s][r];
                }
            }
            h2 lo0 = pack_h2(aL0[s][0], aL0[s][1]);
            h2 hi0 = pack_h2(aL0[s][2], aL0[s][3]);
            h4 p0 = __builtin_shufflevector(lo0, hi0, 0, 1, 2, 3);
            *(h4*)(U.p2.gl2hT[s] + col * 32 + quad * 4) = p0;
            h2 lo1 = pack_h2(aL1[s][0], aL1[s][1]);
            h2 hi1 = pack_h2(aL1[s][2], aL1[s][3]);
            h4 p1 = __builtin_shufflevector(lo1, hi1, 0, 1, 2, 3);
            *(h4*)(U.p2.gl2hT[s] + col * 32 + 16 + quad * 4) = p1;
        }
    }
    __syncthreads();

    // ---- layer-2 logits (abs part) both samples + u2/v2 in spare slots ----
    {
        h2 ar2[32];
        #pragma unroll
        for (int q = 0; q < 32; ++q) ar2[q] = att2Lh[q];

        #pragma unroll
        for (int it = 0; it < 4; ++it) {
            int t = it * 256 + tid;
            if (t < 882) {
                int s = t >= 441;
                int p = t - s * 441;
                int i = p / 21;
                int j = p - i * 21;
                const h8* gA8 = (const h8*)(U.p2.gl2h[s] + j * STR2H);
                const h8* gB8 = (const h8*)(U.p2.gr2h[s] + i * STR2H);
                float m0 = 0.f, m1 = 0.f;
                #pragma unroll
                for (int ch = 0; ch < 8; ++ch) {
                    h8 x = gA8[ch] + gB8[ch];
                    h8 ax = habs8(x);
                    m0 = fdot2(SV(ax, 0, 1), ar2[ch * 4 + 0], m0);
                    m1 = fdot2(SV(ax, 2, 3), ar2[ch * 4 + 1], m1);
                    m0 = fdot2(SV(ax, 4, 5), ar2[ch * 4 + 2], m0);
                    m1 = fdot2(SV(ax, 6, 7), ar2[ch * 4 + 3], m1);
                }
                U.p2.e2[s][i * 24 + j] = m0 + m1;
            } else if (t < 966) {
                int u = t - 882;                  // 0..83
                int s = u >= 42;
                int r = u - s * 42;
                int isV = r >= 21;
                int idx = r - isV * 21;
                const _Float16* rowp = (isV ? U.p2.gr2h[s] : U.p2.gl2h[s]) + idx * STR2H;
                const h8* row8 = (const h8*)rowp;
                float l0 = 0.f, l1 = 0.f;
                #pragma unroll
                for (int ch = 0; ch < 8; ++ch) {
                    h8 g = row8[ch];
                    l0 = fdot2(SV(g, 0, 1), ar2[ch * 4 + 0], l0);
                    l1 = fdot2(SV(g, 2, 3), ar2[ch * 4 + 1], l1);
                    l0 = fdot2(SV(g, 4, 5), ar2[ch * 4 + 2], l0);
                    l1 = fdot2(SV(g, 6, 7), ar2[ch * 4 + 3], l1);
                }
                U.p2.u2v2[s][isV * 21 + idx] = l0 + l1;
            }
        }
    }
    __syncthreads();

    // ---- softmax-2 both samples -> fp16 A-frag; zero rows 21..31 both ----
    if (tid < 42) {
        int s = tid >= 21;
        int i = tid - s * 21;
        float* row = U.p2.e2[s] + i * 24;
        const float* uu = U.p2.u2v2[s];
        float vi = 1.5f * U.p2.u2v2[s][21 + i];
        float ebuf[21];
        float m = -1e30f;
        #pragma unroll
        for (int j = 0; j < 21; j++) {
            float e = row[j] + 1.5f * uu[j] + vi;
            ebuf[j] = e;
            m = fmaxf(m, e);
        }
        float sum = 0.f;
        #pragma unroll
        for (int j = 0; j < 21; j++) { float v = __expf(ebuf[j] - m); ebuf[j] = v; sum += v; }
        float rinv = 1.f / sum;
        h8* hp8 = (h8*)(U.p2.e2[s]) + i * 6;
        h8 o0, o1, o2;
        #pragma unroll
        for (int q = 0; q < 8; ++q) o0[q] = (_Float16)(ebuf[q] * rinv);
        #pragma unroll
        for (int q = 0; q < 8; ++q) o1[q] = (_Float16)(ebuf[8 + q] * rinv);
        #pragma unroll
        for (int q = 0; q < 5; ++q) o2[q] = (_Float16)(ebuf[16 + q] * rinv);
        o2[5] = (_Float16)0.f; o2[6] = (_Float16)0.f; o2[7] = (_Float16)0.f;
        h8 zz = {};
        hp8[0] = o0; hp8[1] = o1; hp8[2] = o2;
        hp8[3] = zz; hp8[4] = zz; hp8[5] = zz;
    } else if (tid < 174) {
        int z = tid - 42;                 // 0..131: rows 21..31 x 6 slots x 2 samples
        int s = z >= 66;
        int zz2 = z - s * 66;
        int rr = zz2 / 6, slot = zz2 - rr * 6;
        h8 zz = {};
        ((h8*)U.p2.e2[s])[(21 + rr) * 6 + slot] = zz;
    }
    __syncthreads();

    // ---- agg2 + mean-pool via MFMA -> nfvh, both samples ----
    {
        const int lane = tid & 63;
        const int w = tid >> 6;
        const int mcol = lane & 15;
        const int quad = lane >> 4;
        const int col = w * 16 + mcol;
        float bb = b2[col];
        f32x4 z4 = {0.f, 0.f, 0.f, 0.f};
        #pragma unroll
        for (int s = 0; s < 2; ++s) {
            const h8* Af2 = (const h8*)U.p2.e2[s];
            h8 A0 = Af2[mcol * 6 + quad];
            h8 A1 = Af2[(16 + mcol) * 6 + quad];
            h8 bv = *(const h8*)(U.p2.gl2hT[s] + col * 32 + quad * 8);
            f32x4 d0 = mfma16(A0, bv, z4);
            f32x4 d1 = mfma16(A1, bv, z4);
            float sum = (d0[0] + d0[1]) + (d0[2] + d0[3])
                      + (d1[0] + d1[1]) + (d1[2] + d1[3]);
            sum += __shfl_xor(sum, 16, 64);
            sum += __shfl_xor(sum, 32, 64);
            if (quad == 0) U.p2.nfvh[s][col] = (_Float16)(sum * (1.f / 21.f) + bb);
        }
    }
    __syncthreads();

    // ---- FC1 (64 -> 256): weights loaded once, both samples ----
    {
        int c = tid & 63, g = tid >> 6;
        float4 acc0 = {0.f, 0.f, 0.f, 0.f}, acc1 = {0.f, 0.f, 0.f, 0.f};
        #pragma unroll
        for (int kk = 0; kk < 8; ++kk) {
            int k2 = g * 8 + kk;
            h8 w = wsF1[k2 * 64 + c];
            h2 x0 = ((const h2*)U.p2.nfvh[0])[k2];
            h2 x1 = ((const h2*)U.p2.nfvh[1])[k2];
            acc0.x = fdot2(SV(w, 0, 1), x0, acc0.x);
            acc0.y = fdot2(SV(w, 2, 3), x0, acc0.y);
            acc0.z = fdot2(SV(w, 4, 5), x0, acc0.z);
            acc0.w = fdot2(SV(w, 6, 7), x0, acc0.w);
            acc1.x = fdot2(SV(w, 0, 1), x1, acc1.x);
            acc1.y = fdot2(SV(w, 2, 3), x1, acc1.y);
            acc1.z = fdot2(SV(w, 4, 5), x1, acc1.z);
            acc1.w = fdot2(SV(w, 6, 7), x1, acc1.w);
        }
        ((float4*)U.p2.red[0][g])[c] = acc0;
        ((float4*)U.p2.red[1][g])[c] = acc1;
    }
    __syncthreads();
    {
        float bb = fc1_b[tid];
        #pragma unroll
        for (int s = 0; s < 2; ++s) {
            float v = U.p2.red[s][0][tid] + U.p2.red[s][1][tid]
                    + U.p2.red[s][2][tid] + U.p2.red[s][3][tid] + bb;
            U.p2.hah[s][tid] = (_Float16)fmaxf(v, 0.f);
        }
    }
    __syncthreads();

    // ---- FC2 (256 -> 256): weights loaded once, both samples ----
    {
        int c = tid & 63, g = tid >> 6;
        const h8* ha0 = (const h8*)U.p2.hah[0];
        const h8* ha1 = (const h8*)U.p2.hah[1];
        float4 acc0 = {0.f, 0.f, 0.f, 0.f}, acc1 = {0.f, 0.f, 0.f, 0.f};
#define FC2_STEP(q, p)                                                          \
        {                                                                       \
            int k2 = g * 32 + (q) * 4 + (p);                                    \
            h8 w = wsF2[k2 * 64 + c];                                           \
            h2 x0 = __builtin_shufflevector(xa0, xa0, 2 * (p), 2 * (p) + 1);    \
            h2 x1 = __builtin_shufflevector(xa1, xa1, 2 * (p), 2 * (p) + 1);    \
            acc0.x = fdot2(SV(w, 0, 1), x0, acc0.x);                            \
            acc0.y = fdot2(SV(w, 2, 3), x0, acc0.y);                            \
            acc0.z = fdot2(SV(w, 4, 5), x0, acc0.z);                            \
            acc0.w = fdot2(SV(w, 6, 7), x0, acc0.w);                            \
            acc1.x = fdot2(SV(w, 0, 1), x1, acc1.x);                            \
            acc1.y = fdot2(SV(w, 2, 3), x1, acc1.y);                            \
            acc1.z = fdot2(SV(w, 4, 5), x1, acc1.z);                            \
            acc1.w = fdot2(SV(w, 6, 7), x1, acc1.w);                            \
        }
        #pragma unroll
        for (int q = 0; q < 8; ++q) {
            h8 xa0 = ha0[g * 8 + q];
            h8 xa1 = ha1[g * 8 + q];
            FC2_STEP(q, 0)
            FC2_STEP(q, 1)
            FC2_STEP(q, 2)
            FC2_STEP(q, 3)
        }
#undef FC2_STEP
        ((float4*)U.p2.red[0][g])[c] = acc0;
        ((float4*)U.p2.red[1][g])[c] = acc1;
    }
    __syncthreads();
    {
        float bb = fc2_b[tid];
        #pragma unroll
        for (int s = 0; s < 2; ++s) {
            float v = U.p2.red[s][0][tid] + U.p2.red[s][1][tid]
                    + U.p2.red[s][2][tid] + U.p2.red[s][3][tid] + bb;
            U.p2.hbh[s][tid] = (_Float16)fmaxf(v, 0.f);
        }
    }
    __syncthreads();

    // ---- FC3 (256 -> 2) + tanh: 4 wave-groups = (o, s) pairs ----
    {
        int g = tid >> 6;                 // 0..3
        int o = g & 1, s = g >> 1;
        int l = tid & 63;
        float sum = 0.f;
        #pragma unroll
        for (int m = 0; m < 4; m++) {
            int k = l + 64 * m;
            sum = fmaf((float)U.p2.hbh[s][k], fc3_w[k * 2 + o], sum);
        }
        #pragma unroll
        for (int off = 32; off >= 1; off >>= 1) sum += __shfl_down(sum, off, 64);
        if (l == 0 && smp0 + s < B) out[(smp0 + s) * 2 + o] = tanhf(sum + fc3_b[o]);
    }
}

extern "C" void kernel_launch(void* const* d_in, const int* in_sizes, int n_in,
                              void* d_out, int out_size, void* d_ws, size_t ws_size,
                              hipStream_t stream) {
    const float* state24 = (const float*)d_in[0];
    const float* Wl1 = (const float*)d_in[1];
    const float* Wr1 = (const float*)d_in[2];
    const float* att1 = (const float*)d_in[3];
    const float* b1 = (const float*)d_in[4];
    const float* Wl2 = (const float*)d_in[5];
    const float* Wr2 = (const float*)d_in[6];
    const float* att2 = (const float*)d_in[7];
    const float* b2 = (const float*)d_in[8];
    const float* fc1_w = (const float*)d_in[9];
    const float* fc1_b = (const float*)d_in[10];
    const float* fc2_w = (const float*)d_in[11];
    const float* fc2_b = (const float*)d_in[12];
    const float* fc3_w = (const float*)d_in[13];
    const float* fc3_b = (const float*)d_in[14];
    float* out = (float*)d_out;

    h8* ws = (h8*)d_ws;                 // 14336 h8 = 224 KiB
    const h8* wsL = ws;
    const h8* wsR = ws + 2048;
    const h8* wsF1 = ws + 4096;
    const h8* wsF2 = ws + 6144;

    pack_weights_kernel<<<56, 256, 0, stream>>>(Wl2, Wr2, fc1_w, fc2_w, ws);

    int B = in_sizes[0] / 24;
    int nb = (B + 1) / 2;
    actor_fused_kernel<<<nb, 256, 0, stream>>>(
        state24, Wl1, Wr1, att1, b1, att2, b2,
        fc1_b, fc2_b, fc3_w, fc3_b,
        wsL, wsR, wsF1, wsF2, out, B);
}